// Round 6
// baseline (550.541 us; speedup 1.0000x reference)
//
#include <hip/hip_runtime.h>
#include <hip/hip_bf16.h>

// Grouped experts GEMM: out[t, o] = sum_k input[t,k] * weight[e(t), o, k] + bias[e(t), o]
// E=8, T=32768, DIN(K)=1024, DOUT(N)=4096.
//
// Round 6: round-4 persistent 256x256/8-wave core, but B-operand loaded
// DIRECTLY global->VGPR (L2/L1-served, 2x reuse via L1) instead of LDS
// staging. A stays LDS-staged (4x reuse). Cuts LDS reads 33%, LDS DMA
// writes 50%, one barrier per K-tile. LDS now 64 KiB (A dbuf only).

#define DEVFN __device__ __forceinline__

constexpr int E_    = 8;
constexpr int T_    = 32768;
constexpr int DIN_  = 1024;   // K
constexpr int DOUT_ = 4096;   // N

typedef __attribute__((ext_vector_type(8))) __bf16 bf16x8;   // MFMA A/B frag (4 VGPR)
typedef __attribute__((ext_vector_type(4))) float  f32x4;    // MFMA C/D frag
typedef __attribute__((ext_vector_type(8))) short  s16x8;

DEVFN unsigned short f2bf(float x) {
  unsigned u = __builtin_bit_cast(unsigned, x);
  u += 0x7fffu + ((u >> 16) & 1u);
  return (unsigned short)(u >> 16);
}

DEVFN long long expert_offset(const void* cnts, int e) {
  const int* c32 = (const int*)cnts;
  long long s = 0;
  for (int i = 0; i < E_; ++i) s += c32[i];
  if (s == (long long)T_) {
    long long o = 0;
    for (int i = 0; i < e; ++i) o += c32[i];
    return o;
  }
  const long long* c64 = (const long long*)cnts;
  long long o = 0;
  for (int i = 0; i < e; ++i) o += c64[i];
  return o;
}

// Combined f32->bf16 conversion for input (nA4 float4s) and weight (nW4).
__global__ __launch_bounds__(256) void cvt2_kernel(const float* __restrict__ ia,
                                                   const float* __restrict__ iw,
                                                   unsigned short* __restrict__ oa,
                                                   unsigned short* __restrict__ ow,
                                                   int nA4, int nW4) {
  int i = blockIdx.x * 256 + threadIdx.x;
  const float* src;
  unsigned short* dst;
  int j;
  if (i < nA4) { src = ia; dst = oa; j = i; }
  else         { j = i - nA4; if (j >= nW4) return; src = iw; dst = ow; }
  const float4 f = reinterpret_cast<const float4*>(src)[j];
  ushort4 h;
  h.x = f2bf(f.x); h.y = f2bf(f.y); h.z = f2bf(f.z); h.w = f2bf(f.w);
  reinterpret_cast<ushort4*>(dst)[j] = h;
}

// ---------------------------------------------------------------------------
// Persistent grouped GEMM: 256 blocks x 512 threads; block p -> expert e=p&7
// (XCD-local), q=p>>3 in [0,32). 8 tiles per block:
//   tm = (it&3)*4 + (q>>3), tn = (it>>2)*8 + (q&7)   (B panel reused 4 its)
// Per tile: 256x256, 8 waves (2Mx4N), per-wave 128x64 = acc[8][4]. BK=64.
// A: LDS-staged, 2 x 32KB dbuf, granule swizzle c^=(r&7) on pre-swizzled
//    global source + ds_read address (involution).
// B: direct global->VGPR loads of the 8 frags per K-tile (coalesces to 64B
//    segments across lanes {rsel, hi}; 2nd read of each line is an L1 hit).
// K-tile (2 barriers):
//   R1: issue 8 b-loads; 16 a ds_reads; Q(0,0) Q(0,1) Q(4,1)     BARRIER
//   R2: stage A(kt+2); Q(4,0); vmcnt(4)                          BARRIER
// kt14/15 stage next tile's kt0/1 -> seamless 128-K-tile pipeline.
// ---------------------------------------------------------------------------
__global__ __launch_bounds__(512, 2) void gemm6_kernel(const unsigned short* __restrict__ wa,
                                                       const unsigned short* __restrict__ wb,
                                                       const float* __restrict__ bias,
                                                       const void* __restrict__ counts,
                                                       float* __restrict__ out) {
  __shared__ __align__(16) unsigned char lds[2][32768];

  const int tid  = threadIdx.x;
  const int lane = tid & 63;
  const int wid  = tid >> 6;
  const int wm = wid >> 2, wn = wid & 3;   // 2 x 4 wave grid

  const int p = blockIdx.x;
  const int e = p & 7;
  const int q = p >> 3;                    // 0..31

  const long long off = expert_offset(counts, e);
  const unsigned short* wae = wa + off * (long long)DIN_;
  const unsigned short* wbe = wb + (long long)e * DOUT_ * DIN_;
  const float* be = bias + e * DOUT_;

  // A staging: 4 rounds x 512 threads x 16B = 32KB (256 rows x 128B).
  int goff[4];
#pragma unroll
  for (int rd = 0; rd < 4; ++rd) {
    const int chunk = rd * 512 + tid;
    const int r = chunk >> 3, c = chunk & 7;
    goff[rd] = r * DIN_ + ((c ^ (r & 7)) << 3);   // pre-swizzled global element offset
  }
  auto stageA = [&](const unsigned short* g, unsigned char* l) {
#pragma unroll
    for (int rd = 0; rd < 4; ++rd)
      __builtin_amdgcn_global_load_lds(
          (const __attribute__((address_space(1))) void*)(g + goff[rd]),
          (__attribute__((address_space(3))) void*)(l + (rd * 512 + tid) * 16), 16, 0, 0);
  };

  const int rsel = lane & 15, hi = lane >> 4;
  int lp[2];
  lp[0] = rsel * 128 + (((hi)     ^ (rsel & 7)) << 4);
  lp[1] = rsel * 128 + (((4 + hi) ^ (rsel & 7)) << 4);
  const int abase = wm * 128 * 128;   // wave's A-row block byte offset in LDS

  bf16x8 a[4][2];        // A frags for current mq
  bf16x8 b[2][2][2];     // B frags [nq][j][kk], loaded direct from global
  f32x4  acc[8][4];      // [mq*4+mf][nf]

  auto quad = [&](int am0, int qn) {
#pragma unroll
    for (int mf = 0; mf < 4; ++mf)
#pragma unroll
      for (int j = 0; j < 2; ++j)
#pragma unroll
        for (int kk = 0; kk < 2; ++kk)
          acc[am0 + mf][qn * 2 + j] = __builtin_amdgcn_mfma_f32_16x16x32_bf16(
              a[mf][kk], b[qn][j][kk], acc[am0 + mf][qn * 2 + j], 0, 0, 0);
  };

  int tm = q >> 3, tn = q & 7;
  const unsigned short* wat = wae + (long long)tm * 256 * DIN_;
  const unsigned short* wbt = wbe + (long long)tn * 256 * DIN_;
  stageA(wat,      &lds[0][0]);
  stageA(wat + 64, &lds[1][0]);
  asm volatile("s_waitcnt vmcnt(4)" ::: "memory");   // K-tile 0 A landed
  __builtin_amdgcn_s_barrier();

  for (int it = 0; it < 8; ++it) {
    const int ocol0 = tn * 256 + wn * 64;
    // B frag row base pointers for this tile (lane-fixed rows).
    const unsigned short* bptr[2][2];
#pragma unroll
    for (int nq = 0; nq < 2; ++nq)
#pragma unroll
      for (int j = 0; j < 2; ++j)
        bptr[nq][j] = wbt + (long long)(wn * 64 + nq * 32 + j * 16 + rsel) * DIN_ + hi * 8;
    // Bias folded into accumulator init (epilogue becomes pure stores).
    {
      const float bv0 = be[ocol0 + rsel];
      const float bv1 = be[ocol0 + 16 + rsel];
      const float bv2 = be[ocol0 + 32 + rsel];
      const float bv3 = be[ocol0 + 48 + rsel];
#pragma unroll
      for (int am = 0; am < 8; ++am) {
        acc[am][0] = (f32x4){bv0, bv0, bv0, bv0};
        acc[am][1] = (f32x4){bv1, bv1, bv1, bv1};
        acc[am][2] = (f32x4){bv2, bv2, bv2, bv2};
        acc[am][3] = (f32x4){bv3, bv3, bv3, bv3};
      }
    }
    const bool have_next = (it < 7);
    int ntm = tm, ntn = tn;
    if (have_next) { ntm = ((it + 1) & 3) * 4 + (q >> 3); ntn = ((it + 1) >> 2) * 8 + (q & 7); }
    const unsigned short* nat = wae + (long long)ntm * 256 * DIN_;
    const unsigned short* nbt = wbe + (long long)ntn * 256 * DIN_;

    for (int kt = 0; kt < 16; ++kt) {
      unsigned char* Ab = &lds[kt & 1][0];
      const unsigned short* pfa = nullptr;
      int nend = -1;
      if (kt < 14)        { pfa = wat + (kt + 2) * 64; nend = 4; }
      else if (have_next) { pfa = nat + (kt - 14) * 64; nend = 4; }
      else if (kt == 14)  { nend = 0; }

      // ---- R1: issue B loads, A ds_reads, quadrants (0,0),(0,1),(4,1).
#pragma unroll
      for (int nq = 0; nq < 2; ++nq)
#pragma unroll
        for (int j = 0; j < 2; ++j)
#pragma unroll
          for (int kk = 0; kk < 2; ++kk)
            b[nq][j][kk] = *(const bf16x8*)(bptr[nq][j] + kt * 64 + kk * 32);
#pragma unroll
      for (int mf = 0; mf < 4; ++mf) {
        a[mf][0] = *(const bf16x8*)(Ab + abase + mf * 2048 + lp[0]);
        a[mf][1] = *(const bf16x8*)(Ab + abase + mf * 2048 + lp[1]);
      }
      __builtin_amdgcn_s_setprio(1); quad(0, 0); __builtin_amdgcn_s_setprio(0);
      __builtin_amdgcn_s_setprio(1); quad(0, 1); __builtin_amdgcn_s_setprio(0);
#pragma unroll
      for (int mf = 0; mf < 4; ++mf) {
        a[mf][0] = *(const bf16x8*)(Ab + abase + 8192 + mf * 2048 + lp[0]);
        a[mf][1] = *(const bf16x8*)(Ab + abase + 8192 + mf * 2048 + lp[1]);
      }
      __builtin_amdgcn_s_setprio(1); quad(4, 1); __builtin_amdgcn_s_setprio(0);
      __builtin_amdgcn_s_barrier();            // all waves' A reads of kt complete

      // ---- R2: stage A(kt+2) into freed A buffer, last quadrant, counted vmcnt.
      if (pfa) stageA(pfa, Ab);
      __builtin_amdgcn_sched_barrier(0);       // staging issues before MFMA cluster
      __builtin_amdgcn_s_setprio(1); quad(4, 0); __builtin_amdgcn_s_setprio(0);
      if (nend == 4)      asm volatile("s_waitcnt vmcnt(4)" ::: "memory");
      else if (nend == 0) asm volatile("s_waitcnt vmcnt(0)" ::: "memory");
      __builtin_amdgcn_s_barrier();
    }

    // Epilogue: pure stores (bias already in acc). col=lane&15, row=(lane>>4)*4+j.
    const long long orow0 = off + (long long)tm * 256 + wm * 128;
#pragma unroll
    for (int am = 0; am < 8; ++am) {
      const int rl = (am >> 2) * 64 + (am & 3) * 16 + hi * 4;
#pragma unroll
      for (int j = 0; j < 4; ++j) {
        float* rp = out + (orow0 + rl + j) * (long long)DOUT_ + ocol0 + rsel;
        rp[0]  = acc[am][0][j];
        rp[16] = acc[am][1][j];
        rp[32] = acc[am][2][j];
        rp[48] = acc[am][3][j];
      }
    }
    wat = nat; wbt = nbt; tm = ntm; tn = ntn;
  }
}

// ---------------------------------------------------------------------------
// Fallback (ws too small): 128x128, reg-staged f32->bf16 (round-1 proven).
// ---------------------------------------------------------------------------
__global__ __launch_bounds__(256) void gemm_fb_kernel(const float* __restrict__ Af,
                                                      const float* __restrict__ Bf,
                                                      const float* __restrict__ bias,
                                                      const void* __restrict__ counts,
                                                      float* __restrict__ out) {
  constexpr int RS = 144;
  constexpr int BBASE = 128 * RS;
  __shared__ __align__(16) unsigned char lds[2 * 128 * RS];

  const int tid  = threadIdx.x;
  const int lane = tid & 63;
  const int wid  = tid >> 6;
  const int wm = wid >> 1, wn = wid & 1;

  const int bid = blockIdx.x;
  const int e  = bid >> 10;
  const int t  = bid & 1023;
  const int tm = t >> 5, tn = t & 31;

  const long long off = expert_offset(counts, e);
  const long long rowA0 = off + (long long)tm * 128;
  const int n0 = tn * 128;

  f32x4 acc[4][4] = {};

  for (int kt = 0; kt < DIN_ / 64; ++kt) {
    const int k0 = kt * 64;
#pragma unroll
    for (int rd = 0; rd < 8; ++rd) {
      const int chunk = rd * 256 + tid;
      const int c2 = chunk & 1023;
      const int r  = c2 >> 3;
      const int c  = c2 & 7;
      const float* src =
          (rd < 4) ? (Af + (rowA0 + r) * (long long)DIN_ + (k0 + c * 8))
                   : (Bf + ((long long)(e * DOUT_ + n0 + r)) * DIN_ + (k0 + c * 8));
      const float4 f0 = *reinterpret_cast<const float4*>(src);
      const float4 f1 = *reinterpret_cast<const float4*>(src + 4);
      s16x8 v;
      v[0] = (short)f2bf(f0.x); v[1] = (short)f2bf(f0.y);
      v[2] = (short)f2bf(f0.z); v[3] = (short)f2bf(f0.w);
      v[4] = (short)f2bf(f1.x); v[5] = (short)f2bf(f1.y);
      v[6] = (short)f2bf(f1.z); v[7] = (short)f2bf(f1.w);
      *reinterpret_cast<s16x8*>(&lds[((rd < 4) ? 0 : BBASE) + r * RS + (c << 4)]) = v;
    }
    __syncthreads();
#pragma unroll
    for (int kk = 0; kk < 2; ++kk) {
      const int rs = lane & 15;
      const int cs = kk * 4 + (lane >> 4);
      bf16x8 af[4], bfr[4];
#pragma unroll
      for (int mf = 0; mf < 4; ++mf)
        af[mf] = *reinterpret_cast<const bf16x8*>(&lds[(wm * 64 + mf * 16 + rs) * RS + (cs << 4)]);
#pragma unroll
      for (int nf = 0; nf < 4; ++nf)
        bfr[nf] = *reinterpret_cast<const bf16x8*>(&lds[BBASE + (wn * 64 + nf * 16 + rs) * RS + (cs << 4)]);
#pragma unroll
      for (int mf = 0; mf < 4; ++mf)
#pragma unroll
        for (int nf = 0; nf < 4; ++nf)
          acc[mf][nf] = __builtin_amdgcn_mfma_f32_16x16x32_bf16(af[mf], bfr[nf], acc[mf][nf], 0, 0, 0);
    }
    __syncthreads();
  }

  const long long orow0 = off + (long long)tm * 128 + wm * 64;
  const int ocol0 = n0 + wn * 64;
  const int rlo = (lane >> 4) * 4;
  const int c15 = lane & 15;
#pragma unroll
  for (int nf = 0; nf < 4; ++nf) {
    const int n = ocol0 + nf * 16 + c15;
    const float bv = bias[e * DOUT_ + n];
#pragma unroll
    for (int mf = 0; mf < 4; ++mf) {
      const long long mrow = orow0 + mf * 16 + rlo;
#pragma unroll
      for (int j = 0; j < 4; ++j)
        out[(mrow + j) * (long long)DOUT_ + n] = acc[mf][nf][j] + bv;
    }
  }
}

extern "C" void kernel_launch(void* const* d_in, const int* in_sizes, int n_in,
                              void* d_out, int out_size, void* d_ws, size_t ws_size,
                              hipStream_t stream) {
  const float* input  = (const float*)d_in[0];
  const float* weight = (const float*)d_in[1];
  const float* bias   = (const float*)d_in[2];
  const void*  counts = (const void*)d_in[3];
  float* out = (float*)d_out;

  const size_t nA = (size_t)T_ * DIN_;
  const size_t nW = (size_t)E_ * DOUT_ * DIN_;
  const size_t need = (nA + nW) * sizeof(unsigned short);

  if (ws_size >= need) {
    unsigned short* wa = (unsigned short*)d_ws;
    unsigned short* wb = wa + nA;
    const int nA4 = (int)(nA / 4), nW4 = (int)(nW / 4);
    cvt2_kernel<<<dim3((unsigned)((nA4 + nW4) / 256)), dim3(256), 0, stream>>>(
        input, weight, wa, wb, nA4, nW4);
    gemm6_kernel<<<dim3(256), dim3(512), 0, stream>>>(wa, wb, bias, counts, out);
  } else {
    gemm_fb_kernel<<<dim3(E_ * 32 * 32), dim3(256), 0, stream>>>(input, weight, bias, counts, out);
  }
}

// Round 7
// 410.733 us; speedup vs baseline: 1.3404x; 1.3404x over previous
//
#include <hip/hip_runtime.h>
#include <hip/hip_bf16.h>

// Grouped experts GEMM: out[t, o] = sum_k input[t,k] * weight[e(t), o, k] + bias[e(t), o]
// E=8, T=32768, DIN(K)=1024, DOUT(N)=4096.
//
// Round 7: round-4 persistent 256x256/8-wave core + carried-quadrant software
// pipeline: Q(4,1) of K-tile kt executes at the START of kt+1's region, as a
// register-only MFMA cluster that fills the post-barrier LDS read-burst dead
// time. Named operand buffers (a0/a1/b0/b1) keep max liveness == round 4
// (~248 regs). 2 barriers/K-tile. B stays in LDS (round 6 showed B-direct is
// L2-BW-bound). cvt kernels merged (round 5, neutral).

#define DEVFN __device__ __forceinline__

constexpr int E_    = 8;
constexpr int T_    = 32768;
constexpr int DIN_  = 1024;   // K
constexpr int DOUT_ = 4096;   // N

typedef __attribute__((ext_vector_type(8))) __bf16 bf16x8;   // MFMA A/B frag (4 VGPR)
typedef __attribute__((ext_vector_type(4))) float  f32x4;    // MFMA C/D frag
typedef __attribute__((ext_vector_type(8))) short  s16x8;

DEVFN unsigned short f2bf(float x) {
  unsigned u = __builtin_bit_cast(unsigned, x);
  u += 0x7fffu + ((u >> 16) & 1u);
  return (unsigned short)(u >> 16);
}

DEVFN long long expert_offset(const void* cnts, int e) {
  const int* c32 = (const int*)cnts;
  long long s = 0;
  for (int i = 0; i < E_; ++i) s += c32[i];
  if (s == (long long)T_) {
    long long o = 0;
    for (int i = 0; i < e; ++i) o += c32[i];
    return o;
  }
  const long long* c64 = (const long long*)cnts;
  long long o = 0;
  for (int i = 0; i < e; ++i) o += c64[i];
  return o;
}

// Combined f32->bf16 conversion for input (nA4 float4s) and weight (nW4).
__global__ __launch_bounds__(256) void cvt2_kernel(const float* __restrict__ ia,
                                                   const float* __restrict__ iw,
                                                   unsigned short* __restrict__ oa,
                                                   unsigned short* __restrict__ ow,
                                                   int nA4, int nW4) {
  int i = blockIdx.x * 256 + threadIdx.x;
  const float* src;
  unsigned short* dst;
  int j;
  if (i < nA4) { src = ia; dst = oa; j = i; }
  else         { j = i - nA4; if (j >= nW4) return; src = iw; dst = ow; }
  const float4 f = reinterpret_cast<const float4*>(src)[j];
  ushort4 h;
  h.x = f2bf(f.x); h.y = f2bf(f.y); h.z = f2bf(f.z); h.w = f2bf(f.w);
  reinterpret_cast<ushort4*>(dst)[j] = h;
}

// ---------------------------------------------------------------------------
// Persistent grouped GEMM: 256 blocks x 512 threads; block p -> expert e=p&7
// (XCD-local), q=p>>3 in [0,32). 8 tiles per block:
//   tm = (it&3)*4 + (q>>3), tn = (it>>2)*8 + (q&7)
// Per tile: 256x256, 8 waves (2Mx4N), per-wave 128x64 = acc[8][4]. BK=64.
// LDS: 2 buffers x (A 32KB + B 32KB) = 128 KiB; granule swizzle c^=(r&7) on
// pre-swizzled global source + ds_read address (involution).
// K-tile (2 barriers), carried-quadrant pipeline:
//   R1: issue reads b0,a0 ; Q(4,1)[kt-1] (register-ready, covers read burst)
//       issue reads a1,b1 ; Q(0,0) Q(0,1) Q(4,0) ; lgkmcnt(0) ; BARRIER
//   R2: stage B(kt+2) ; stage A(kt+2) ; vmcnt(8) ; BARRIER
// Q(4,1)[kt] carries into kt+1; flushed before each tile's epilogue.
// kt14/15 stage next tile's kt0/1 -> seamless 128-K-tile pipeline.
// ---------------------------------------------------------------------------
__global__ __launch_bounds__(512, 2) void gemm7_kernel(const unsigned short* __restrict__ wa,
                                                       const unsigned short* __restrict__ wb,
                                                       const float* __restrict__ bias,
                                                       const void* __restrict__ counts,
                                                       float* __restrict__ out) {
  __shared__ __align__(16) unsigned char lds[2][2][32768];

  const int tid  = threadIdx.x;
  const int lane = tid & 63;
  const int wid  = tid >> 6;
  const int wm = wid >> 2, wn = wid & 3;   // 2 x 4 wave grid

  const int p = blockIdx.x;
  const int e = p & 7;
  const int q = p >> 3;                    // 0..31

  const long long off = expert_offset(counts, e);
  const unsigned short* wae = wa + off * (long long)DIN_;
  const unsigned short* wbe = wb + (long long)e * DOUT_ * DIN_;
  const float* be = bias + e * DOUT_;

  int goff[4];
#pragma unroll
  for (int rd = 0; rd < 4; ++rd) {
    const int chunk = rd * 512 + tid;
    const int r = chunk >> 3, c = chunk & 7;
    goff[rd] = r * DIN_ + ((c ^ (r & 7)) << 3);   // pre-swizzled global element offset
  }
  auto stage = [&](const unsigned short* g, unsigned char* l) {
#pragma unroll
    for (int rd = 0; rd < 4; ++rd)
      __builtin_amdgcn_global_load_lds(
          (const __attribute__((address_space(1))) void*)(g + goff[rd]),
          (__attribute__((address_space(3))) void*)(l + (rd * 512 + tid) * 16), 16, 0, 0);
  };

  const int rsel = lane & 15, hi = lane >> 4;
  int lp[2];
  lp[0] = rsel * 128 + (((hi)     ^ (rsel & 7)) << 4);
  lp[1] = rsel * 128 + (((4 + hi) ^ (rsel & 7)) << 4);
  const int abase = wm * 128 * 128;
  const int bbase = wn * 64 * 128;

  bf16x8 a0r[4][2], a1r[4][2];   // A frags, mq0 / mq1
  bf16x8 b0r[2][2], b1r[2][2];   // B frags, nq0 / nq1
  f32x4  acc[8][4];              // [mq*4+mf][nf]

  auto quad = [&](int am0, int qn, bf16x8 (&A)[4][2], bf16x8 (&B)[2][2]) {
#pragma unroll
    for (int mf = 0; mf < 4; ++mf)
#pragma unroll
      for (int j = 0; j < 2; ++j)
#pragma unroll
        for (int kk = 0; kk < 2; ++kk)
          acc[am0 + mf][qn * 2 + j] = __builtin_amdgcn_mfma_f32_16x16x32_bf16(
              A[mf][kk], B[j][kk], acc[am0 + mf][qn * 2 + j], 0, 0, 0);
  };

  int tm = q >> 3, tn = q & 7;
  const unsigned short* wat = wae + (long long)tm * 256 * DIN_;
  const unsigned short* wbt = wbe + (long long)tn * 256 * DIN_;
  stage(wat,      &lds[0][0][0]);
  stage(wbt,      &lds[0][1][0]);
  stage(wat + 64, &lds[1][0][0]);
  stage(wbt + 64, &lds[1][1][0]);
  asm volatile("s_waitcnt vmcnt(8)" ::: "memory");   // K-tile 0 landed; 1 in flight
  __builtin_amdgcn_s_barrier();

  for (int it = 0; it < 8; ++it) {
    const int ocol0 = tn * 256 + wn * 64;
    // Bias folded into accumulator init (epilogue becomes pure stores).
    {
      const float bv0 = be[ocol0 + rsel];
      const float bv1 = be[ocol0 + 16 + rsel];
      const float bv2 = be[ocol0 + 32 + rsel];
      const float bv3 = be[ocol0 + 48 + rsel];
#pragma unroll
      for (int am = 0; am < 8; ++am) {
        acc[am][0] = (f32x4){bv0, bv0, bv0, bv0};
        acc[am][1] = (f32x4){bv1, bv1, bv1, bv1};
        acc[am][2] = (f32x4){bv2, bv2, bv2, bv2};
        acc[am][3] = (f32x4){bv3, bv3, bv3, bv3};
      }
    }
    const bool have_next = (it < 7);
    int ntm = tm, ntn = tn;
    if (have_next) { ntm = ((it + 1) & 3) * 4 + (q >> 3); ntn = ((it + 1) >> 2) * 8 + (q & 7); }
    const unsigned short* nat = wae + (long long)ntm * 256 * DIN_;
    const unsigned short* nbt = wbe + (long long)ntn * 256 * DIN_;

    for (int kt = 0; kt < 16; ++kt) {
      unsigned char* Ab = &lds[kt & 1][0][0];
      unsigned char* Bb = &lds[kt & 1][1][0];
      const unsigned short* pfa = nullptr;
      const unsigned short* pfb = nullptr;
      int nend = -1;
      if (kt < 14)        { pfa = wat + (kt + 2) * 64; pfb = wbt + (kt + 2) * 64; nend = 8; }
      else if (have_next) { pfa = nat + (kt - 14) * 64; pfb = nbt + (kt - 14) * 64; nend = 8; }
      else if (kt == 14)  { nend = 0; }

      // ---- R1: issue b0+a0 reads, then carried Q(4,1)[kt-1] (register-only,
      //          fires while reads are in flight), then a1+b1 reads, then the
      //          three current quadrants.
#pragma unroll
      for (int j = 0; j < 2; ++j) {
        b0r[j][0] = *(const bf16x8*)(Bb + bbase + j * 2048 + lp[0]);
        b0r[j][1] = *(const bf16x8*)(Bb + bbase + j * 2048 + lp[1]);
      }
#pragma unroll
      for (int mf = 0; mf < 4; ++mf) {
        a0r[mf][0] = *(const bf16x8*)(Ab + abase + mf * 2048 + lp[0]);
        a0r[mf][1] = *(const bf16x8*)(Ab + abase + mf * 2048 + lp[1]);
      }
      if (kt > 0) {
        __builtin_amdgcn_s_setprio(1);
        quad(4, 1, a1r, b1r);               // carried from kt-1
        __builtin_amdgcn_s_setprio(0);
      }
#pragma unroll
      for (int mf = 0; mf < 4; ++mf) {
        a1r[mf][0] = *(const bf16x8*)(Ab + abase + 8192 + mf * 2048 + lp[0]);
        a1r[mf][1] = *(const bf16x8*)(Ab + abase + 8192 + mf * 2048 + lp[1]);
      }
#pragma unroll
      for (int j = 0; j < 2; ++j) {
        b1r[j][0] = *(const bf16x8*)(Bb + bbase + 4096 + j * 2048 + lp[0]);
        b1r[j][1] = *(const bf16x8*)(Bb + bbase + 4096 + j * 2048 + lp[1]);
      }
      __builtin_amdgcn_s_setprio(1);
      quad(0, 0, a0r, b0r);
      quad(0, 1, a0r, b1r);
      quad(4, 0, a1r, b0r);
      __builtin_amdgcn_s_setprio(0);
      asm volatile("s_waitcnt lgkmcnt(0)" ::: "memory");  // a1/b1 data landed
      __builtin_amdgcn_s_barrier();

      // ---- R2: staging issue + counted vmcnt (kt+1 guaranteed landed).
      if (pfb) stage(pfb, Bb);
      if (pfa) stage(pfa, Ab);
      if (nend == 8)      asm volatile("s_waitcnt vmcnt(8)" ::: "memory");
      else if (nend == 0) asm volatile("s_waitcnt vmcnt(0)" ::: "memory");
      __builtin_amdgcn_s_barrier();
    }

    // Flush the carried quadrant of kt=15, then epilogue.
    __builtin_amdgcn_s_setprio(1);
    quad(4, 1, a1r, b1r);
    __builtin_amdgcn_s_setprio(0);

    // Epilogue: pure stores (bias already in acc). col=lane&15, row=(lane>>4)*4+j.
    const long long orow0 = off + (long long)tm * 256 + wm * 128;
#pragma unroll
    for (int am = 0; am < 8; ++am) {
      const int rl = (am >> 2) * 64 + (am & 3) * 16 + hi * 4;
#pragma unroll
      for (int j = 0; j < 4; ++j) {
        float* rp = out + (orow0 + rl + j) * (long long)DOUT_ + ocol0 + rsel;
        rp[0]  = acc[am][0][j];
        rp[16] = acc[am][1][j];
        rp[32] = acc[am][2][j];
        rp[48] = acc[am][3][j];
      }
    }
    wat = nat; wbt = nbt; tm = ntm; tn = ntn;
  }
}

// ---------------------------------------------------------------------------
// Fallback (ws too small): 128x128, reg-staged f32->bf16 (round-1 proven).
// ---------------------------------------------------------------------------
__global__ __launch_bounds__(256) void gemm_fb_kernel(const float* __restrict__ Af,
                                                      const float* __restrict__ Bf,
                                                      const float* __restrict__ bias,
                                                      const void* __restrict__ counts,
                                                      float* __restrict__ out) {
  constexpr int RS = 144;
  constexpr int BBASE = 128 * RS;
  __shared__ __align__(16) unsigned char lds[2 * 128 * RS];

  const int tid  = threadIdx.x;
  const int lane = tid & 63;
  const int wid  = tid >> 6;
  const int wm = wid >> 1, wn = wid & 1;

  const int bid = blockIdx.x;
  const int e  = bid >> 10;
  const int t  = bid & 1023;
  const int tm = t >> 5, tn = t & 31;

  const long long off = expert_offset(counts, e);
  const long long rowA0 = off + (long long)tm * 128;
  const int n0 = tn * 128;

  f32x4 acc[4][4] = {};

  for (int kt = 0; kt < DIN_ / 64; ++kt) {
    const int k0 = kt * 64;
#pragma unroll
    for (int rd = 0; rd < 8; ++rd) {
      const int chunk = rd * 256 + tid;
      const int c2 = chunk & 1023;
      const int r  = c2 >> 3;
      const int c  = c2 & 7;
      const float* src =
          (rd < 4) ? (Af + (rowA0 + r) * (long long)DIN_ + (k0 + c * 8))
                   : (Bf + ((long long)(e * DOUT_ + n0 + r)) * DIN_ + (k0 + c * 8));
      const float4 f0 = *reinterpret_cast<const float4*>(src);
      const float4 f1 = *reinterpret_cast<const float4*>(src + 4);
      s16x8 v;
      v[0] = (short)f2bf(f0.x); v[1] = (short)f2bf(f0.y);
      v[2] = (short)f2bf(f0.z); v[3] = (short)f2bf(f0.w);
      v[4] = (short)f2bf(f1.x); v[5] = (short)f2bf(f1.y);
      v[6] = (short)f2bf(f1.z); v[7] = (short)f2bf(f1.w);
      *reinterpret_cast<s16x8*>(&lds[((rd < 4) ? 0 : BBASE) + r * RS + (c << 4)]) = v;
    }
    __syncthreads();
#pragma unroll
    for (int kk = 0; kk < 2; ++kk) {
      const int rs = lane & 15;
      const int cs = kk * 4 + (lane >> 4);
      bf16x8 af[4], bfr[4];
#pragma unroll
      for (int mf = 0; mf < 4; ++mf)
        af[mf] = *reinterpret_cast<const bf16x8*>(&lds[(wm * 64 + mf * 16 + rs) * RS + (cs << 4)]);
#pragma unroll
      for (int nf = 0; nf < 4; ++nf)
        bfr[nf] = *reinterpret_cast<const bf16x8*>(&lds[BBASE + (wn * 64 + nf * 16 + rs) * RS + (cs << 4)]);
#pragma unroll
      for (int mf = 0; mf < 4; ++mf)
#pragma unroll
        for (int nf = 0; nf < 4; ++nf)
          acc[mf][nf] = __builtin_amdgcn_mfma_f32_16x16x32_bf16(af[mf], bfr[nf], acc[mf][nf], 0, 0, 0);
    }
    __syncthreads();
  }

  const long long orow0 = off + (long long)tm * 128 + wm * 64;
  const int ocol0 = n0 + wn * 64;
  const int rlo = (lane >> 4) * 4;
  const int c15 = lane & 15;
#pragma unroll
  for (int nf = 0; nf < 4; ++nf) {
    const int n = ocol0 + nf * 16 + c15;
    const float bv = bias[e * DOUT_ + n];
#pragma unroll
    for (int mf = 0; mf < 4; ++mf) {
      const long long mrow = orow0 + mf * 16 + rlo;
#pragma unroll
      for (int j = 0; j < 4; ++j)
        out[(mrow + j) * (long long)DOUT_ + n] = acc[mf][nf][j] + bv;
    }
  }
}

extern "C" void kernel_launch(void* const* d_in, const int* in_sizes, int n_in,
                              void* d_out, int out_size, void* d_ws, size_t ws_size,
                              hipStream_t stream) {
  const float* input  = (const float*)d_in[0];
  const float* weight = (const float*)d_in[1];
  const float* bias   = (const float*)d_in[2];
  const void*  counts = (const void*)d_in[3];
  float* out = (float*)d_out;

  const size_t nA = (size_t)T_ * DIN_;
  const size_t nW = (size_t)E_ * DOUT_ * DIN_;
  const size_t need = (nA + nW) * sizeof(unsigned short);

  if (ws_size >= need) {
    unsigned short* wa = (unsigned short*)d_ws;
    unsigned short* wb = wa + nA;
    const int nA4 = (int)(nA / 4), nW4 = (int)(nW / 4);
    cvt2_kernel<<<dim3((unsigned)((nA4 + nW4) / 256)), dim3(256), 0, stream>>>(
        input, weight, wa, wb, nA4, nW4);
    gemm7_kernel<<<dim3(256), dim3(512), 0, stream>>>(wa, wb, bias, counts, out);
  } else {
    gemm_fb_kernel<<<dim3(E_ * 32 * 32), dim3(256), 0, stream>>>(input, weight, bias, counts, out);
  }
}

// Round 8
// 364.665 us; speedup vs baseline: 1.5097x; 1.1263x over previous
//
#include <hip/hip_runtime.h>
#include <hip/hip_bf16.h>

// Grouped experts GEMM: out[t, o] = sum_k input[t,k] * weight[e(t), o, k] + bias[e(t), o]
// E=8, T=32768, DIN(K)=1024, DOUT(N)=4096.
//
// Round 8: revert to the round-4 kernel (best measured: GEMM 310 us, 886 TF,
// above the documented grouped-8ph@K=1024 reference of 848 TF), keeping the
// merged cvt kernel from round 5 (neutral, one fewer launch). Rounds 5-7
// showed every schedule perturbation of this structure regresses.

#define DEVFN __device__ __forceinline__

constexpr int E_    = 8;
constexpr int T_    = 32768;
constexpr int DIN_  = 1024;   // K
constexpr int DOUT_ = 4096;   // N

typedef __attribute__((ext_vector_type(8))) __bf16 bf16x8;   // MFMA A/B frag (4 VGPR)
typedef __attribute__((ext_vector_type(4))) float  f32x4;    // MFMA C/D frag
typedef __attribute__((ext_vector_type(8))) short  s16x8;

DEVFN unsigned short f2bf(float x) {
  unsigned u = __builtin_bit_cast(unsigned, x);
  u += 0x7fffu + ((u >> 16) & 1u);
  return (unsigned short)(u >> 16);
}

DEVFN long long expert_offset(const void* cnts, int e) {
  const int* c32 = (const int*)cnts;
  long long s = 0;
  for (int i = 0; i < E_; ++i) s += c32[i];
  if (s == (long long)T_) {
    long long o = 0;
    for (int i = 0; i < e; ++i) o += c32[i];
    return o;
  }
  const long long* c64 = (const long long*)cnts;
  long long o = 0;
  for (int i = 0; i < e; ++i) o += c64[i];
  return o;
}

// Combined f32->bf16 conversion for input (nA4 float4s) and weight (nW4).
__global__ __launch_bounds__(256) void cvt2_kernel(const float* __restrict__ ia,
                                                   const float* __restrict__ iw,
                                                   unsigned short* __restrict__ oa,
                                                   unsigned short* __restrict__ ow,
                                                   int nA4, int nW4) {
  int i = blockIdx.x * 256 + threadIdx.x;
  const float* src;
  unsigned short* dst;
  int j;
  if (i < nA4) { src = ia; dst = oa; j = i; }
  else         { j = i - nA4; if (j >= nW4) return; src = iw; dst = ow; }
  const float4 f = reinterpret_cast<const float4*>(src)[j];
  ushort4 h;
  h.x = f2bf(f.x); h.y = f2bf(f.y); h.z = f2bf(f.z); h.w = f2bf(f.w);
  reinterpret_cast<ushort4*>(dst)[j] = h;
}

// ---------------------------------------------------------------------------
// Persistent grouped GEMM: 256 blocks x 512 threads; block p -> expert e=p&7
// (XCD-local), q=p>>3 in [0,32). 8 tiles per block:
//   tm = (it&3)*4 + (q>>3), tn = (it>>2)*8 + (q&7)
// Per tile: 256x256, 8 waves (2Mx4N), per-wave 128x64 = acc[8][4]. BK=64.
// LDS: 2 buffers x (A 32KB + B 32KB) = 128 KiB; granule swizzle c^=(r&7)
// applied on pre-swizzled global source + ds_read address (involution).
// K-tile schedule (3 barriers):
//   reads A-mq0, B-nq0 ; MFMA(0,0) ; reads B-nq1 ; MFMA(0,1) ; BARRIER
//   stage B(kt+2) ; reads A-mq1 ; MFMA(4,1) ; BARRIER
//   stage A(kt+2) ; MFMA(4,0) ; vmcnt(8) ; BARRIER
// kt14/15 stage next tile's kt0/1 -> one seamless 128-K-tile pipeline.
// ---------------------------------------------------------------------------
__global__ __launch_bounds__(512, 2) void gemm4_kernel(const unsigned short* __restrict__ wa,
                                                       const unsigned short* __restrict__ wb,
                                                       const float* __restrict__ bias,
                                                       const void* __restrict__ counts,
                                                       float* __restrict__ out) {
  __shared__ __align__(16) unsigned char lds[2][2][32768];

  const int tid  = threadIdx.x;
  const int lane = tid & 63;
  const int wid  = tid >> 6;
  const int wm = wid >> 2, wn = wid & 3;   // 2 x 4 wave grid

  const int p = blockIdx.x;
  const int e = p & 7;
  const int q = p >> 3;                    // 0..31

  const long long off = expert_offset(counts, e);
  const unsigned short* wae = wa + off * (long long)DIN_;
  const unsigned short* wbe = wb + (long long)e * DOUT_ * DIN_;
  const float* be = bias + e * DOUT_;

  int goff[4];
#pragma unroll
  for (int rd = 0; rd < 4; ++rd) {
    const int chunk = rd * 512 + tid;
    const int r = chunk >> 3, c = chunk & 7;
    goff[rd] = r * DIN_ + ((c ^ (r & 7)) << 3);   // pre-swizzled global element offset
  }
  auto stage = [&](const unsigned short* g, unsigned char* l) {
#pragma unroll
    for (int rd = 0; rd < 4; ++rd)
      __builtin_amdgcn_global_load_lds(
          (const __attribute__((address_space(1))) void*)(g + goff[rd]),
          (__attribute__((address_space(3))) void*)(l + (rd * 512 + tid) * 16), 16, 0, 0);
  };

  const int rsel = lane & 15, hi = lane >> 4;
  int lp[2];
  lp[0] = rsel * 128 + (((hi)     ^ (rsel & 7)) << 4);
  lp[1] = rsel * 128 + (((4 + hi) ^ (rsel & 7)) << 4);
  const int abase = wm * 128 * 128;  // wave's A-row block byte offset
  const int bbase = wn * 64 * 128;   // wave's B-row block byte offset

  bf16x8 a[4][2];        // A frags for current mq
  bf16x8 b[2][2][2];     // B frags [nq][j][kk]
  f32x4  acc[8][4];      // [mq*4+mf][nf]

  auto quad = [&](int am0, int qn) {
#pragma unroll
    for (int mf = 0; mf < 4; ++mf)
#pragma unroll
      for (int j = 0; j < 2; ++j)
#pragma unroll
        for (int kk = 0; kk < 2; ++kk)
          acc[am0 + mf][qn * 2 + j] = __builtin_amdgcn_mfma_f32_16x16x32_bf16(
              a[mf][kk], b[qn][j][kk], acc[am0 + mf][qn * 2 + j], 0, 0, 0);
  };

  // Tile 0 pointers + prologue staging (K-tiles 0,1 of tile 0).
  int tm = q >> 3, tn = q & 7;
  const unsigned short* wat = wae + (long long)tm * 256 * DIN_;
  const unsigned short* wbt = wbe + (long long)tn * 256 * DIN_;
  stage(wat,      &lds[0][0][0]);
  stage(wbt,      &lds[0][1][0]);
  stage(wat + 64, &lds[1][0][0]);
  stage(wbt + 64, &lds[1][1][0]);
  asm volatile("s_waitcnt vmcnt(8)" ::: "memory");   // K-tile 0 landed; 1 in flight
  __builtin_amdgcn_s_barrier();

  for (int it = 0; it < 8; ++it) {
    const int ocol0 = tn * 256 + wn * 64;
    // Bias folded into accumulator init (epilogue becomes pure stores).
    {
      const float bv0 = be[ocol0 + rsel];
      const float bv1 = be[ocol0 + 16 + rsel];
      const float bv2 = be[ocol0 + 32 + rsel];
      const float bv3 = be[ocol0 + 48 + rsel];
#pragma unroll
      for (int am = 0; am < 8; ++am) {
        acc[am][0] = (f32x4){bv0, bv0, bv0, bv0};
        acc[am][1] = (f32x4){bv1, bv1, bv1, bv1};
        acc[am][2] = (f32x4){bv2, bv2, bv2, bv2};
        acc[am][3] = (f32x4){bv3, bv3, bv3, bv3};
      }
    }
    const bool have_next = (it < 7);
    int ntm = tm, ntn = tn;
    if (have_next) { ntm = ((it + 1) & 3) * 4 + (q >> 3); ntn = ((it + 1) >> 2) * 8 + (q & 7); }
    const unsigned short* nat = wae + (long long)ntm * 256 * DIN_;
    const unsigned short* nbt = wbe + (long long)ntn * 256 * DIN_;

    for (int kt = 0; kt < 16; ++kt) {
      unsigned char* Ab = &lds[kt & 1][0][0];
      unsigned char* Bb = &lds[kt & 1][1][0];
      const unsigned short* pfa = nullptr;
      const unsigned short* pfb = nullptr;
      int nend = -1;
      if (kt < 14)        { pfa = wat + (kt + 2) * 64; pfb = wbt + (kt + 2) * 64; nend = 8; }
      else if (have_next) { pfa = nat + (kt - 14) * 64; pfb = nbt + (kt - 14) * 64; nend = 8; }
      else if (kt == 14)  { nend = 0; }

      // --- reads A-mq0 + B-nq0, MFMA quadrant (0,0)
#pragma unroll
      for (int mf = 0; mf < 4; ++mf) {
        a[mf][0] = *(const bf16x8*)(Ab + abase + mf * 2048 + lp[0]);
        a[mf][1] = *(const bf16x8*)(Ab + abase + mf * 2048 + lp[1]);
      }
#pragma unroll
      for (int j = 0; j < 2; ++j) {
        b[0][j][0] = *(const bf16x8*)(Bb + bbase + j * 2048 + lp[0]);
        b[0][j][1] = *(const bf16x8*)(Bb + bbase + j * 2048 + lp[1]);
      }
      __builtin_amdgcn_s_setprio(1); quad(0, 0); __builtin_amdgcn_s_setprio(0);
      // --- reads B-nq1, MFMA quadrant (0,1)
#pragma unroll
      for (int j = 0; j < 2; ++j) {
        b[1][j][0] = *(const bf16x8*)(Bb + bbase + 4096 + j * 2048 + lp[0]);
        b[1][j][1] = *(const bf16x8*)(Bb + bbase + 4096 + j * 2048 + lp[1]);
      }
      __builtin_amdgcn_s_setprio(1); quad(0, 1); __builtin_amdgcn_s_setprio(0);
      __builtin_amdgcn_s_barrier();            // all waves' B reads complete
      if (pfb) stage(pfb, Bb);                 // overwrite B region (safe)
      // --- reads A-mq1, MFMA quadrant (4,1)
#pragma unroll
      for (int mf = 0; mf < 4; ++mf) {
        a[mf][0] = *(const bf16x8*)(Ab + abase + 8192 + mf * 2048 + lp[0]);
        a[mf][1] = *(const bf16x8*)(Ab + abase + 8192 + mf * 2048 + lp[1]);
      }
      __builtin_amdgcn_s_setprio(1); quad(4, 1); __builtin_amdgcn_s_setprio(0);
      __builtin_amdgcn_s_barrier();            // all waves' A reads complete
      if (pfa) stage(pfa, Ab);                 // overwrite A region (safe)
      __builtin_amdgcn_sched_barrier(0);       // staging issues before MFMA cluster
      __builtin_amdgcn_s_setprio(1); quad(4, 0); __builtin_amdgcn_s_setprio(0);
      if (nend == 8)      asm volatile("s_waitcnt vmcnt(8)" ::: "memory");
      else if (nend == 0) asm volatile("s_waitcnt vmcnt(0)" ::: "memory");
      __builtin_amdgcn_s_barrier();
    }

    // Epilogue: pure stores (bias already in acc). C/D layout: col=lane&15,
    // row=(lane>>4)*4+j. nf innermost -> 4 consecutive 64B stores = 256B/row.
    const long long orow0 = off + (long long)tm * 256 + wm * 128;
#pragma unroll
    for (int am = 0; am < 8; ++am) {
      const int rl = (am >> 2) * 64 + (am & 3) * 16 + hi * 4;
#pragma unroll
      for (int j = 0; j < 4; ++j) {
        float* rp = out + (orow0 + rl + j) * (long long)DOUT_ + ocol0 + rsel;
        rp[0]  = acc[am][0][j];
        rp[16] = acc[am][1][j];
        rp[32] = acc[am][2][j];
        rp[48] = acc[am][3][j];
      }
    }
    wat = nat; wbt = nbt; tm = ntm; tn = ntn;
  }
}

// ---------------------------------------------------------------------------
// Fallback (ws too small): 128x128, reg-staged f32->bf16 (round-1 proven).
// ---------------------------------------------------------------------------
__global__ __launch_bounds__(256) void gemm_fb_kernel(const float* __restrict__ Af,
                                                      const float* __restrict__ Bf,
                                                      const float* __restrict__ bias,
                                                      const void* __restrict__ counts,
                                                      float* __restrict__ out) {
  constexpr int RS = 144;
  constexpr int BBASE = 128 * RS;
  __shared__ __align__(16) unsigned char lds[2 * 128 * RS];

  const int tid  = threadIdx.x;
  const int lane = tid & 63;
  const int wid  = tid >> 6;
  const int wm = wid >> 1, wn = wid & 1;

  const int bid = blockIdx.x;
  const int e  = bid >> 10;
  const int t  = bid & 1023;
  const int tm = t >> 5, tn = t & 31;

  const long long off = expert_offset(counts, e);
  const long long rowA0 = off + (long long)tm * 128;
  const int n0 = tn * 128;

  f32x4 acc[4][4] = {};

  for (int kt = 0; kt < DIN_ / 64; ++kt) {
    const int k0 = kt * 64;
#pragma unroll
    for (int rd = 0; rd < 8; ++rd) {
      const int chunk = rd * 256 + tid;
      const int c2 = chunk & 1023;
      const int r  = c2 >> 3;
      const int c  = c2 & 7;
      const float* src =
          (rd < 4) ? (Af + (rowA0 + r) * (long long)DIN_ + (k0 + c * 8))
                   : (Bf + ((long long)(e * DOUT_ + n0 + r)) * DIN_ + (k0 + c * 8));
      const float4 f0 = *reinterpret_cast<const float4*>(src);
      const float4 f1 = *reinterpret_cast<const float4*>(src + 4);
      s16x8 v;
      v[0] = (short)f2bf(f0.x); v[1] = (short)f2bf(f0.y);
      v[2] = (short)f2bf(f0.z); v[3] = (short)f2bf(f0.w);
      v[4] = (short)f2bf(f1.x); v[5] = (short)f2bf(f1.y);
      v[6] = (short)f2bf(f1.z); v[7] = (short)f2bf(f1.w);
      *reinterpret_cast<s16x8*>(&lds[((rd < 4) ? 0 : BBASE) + r * RS + (c << 4)]) = v;
    }
    __syncthreads();
#pragma unroll
    for (int kk = 0; kk < 2; ++kk) {
      const int rs = lane & 15;
      const int cs = kk * 4 + (lane >> 4);
      bf16x8 af[4], bfr[4];
#pragma unroll
      for (int mf = 0; mf < 4; ++mf)
        af[mf] = *reinterpret_cast<const bf16x8*>(&lds[(wm * 64 + mf * 16 + rs) * RS + (cs << 4)]);
#pragma unroll
      for (int nf = 0; nf < 4; ++nf)
        bfr[nf] = *reinterpret_cast<const bf16x8*>(&lds[BBASE + (wn * 64 + nf * 16 + rs) * RS + (cs << 4)]);
#pragma unroll
      for (int mf = 0; mf < 4; ++mf)
#pragma unroll
        for (int nf = 0; nf < 4; ++nf)
          acc[mf][nf] = __builtin_amdgcn_mfma_f32_16x16x32_bf16(af[mf], bfr[nf], acc[mf][nf], 0, 0, 0);
    }
    __syncthreads();
  }

  const long long orow0 = off + (long long)tm * 128 + wm * 64;
  const int ocol0 = n0 + wn * 64;
  const int rlo = (lane >> 4) * 4;
  const int c15 = lane & 15;
#pragma unroll
  for (int nf = 0; nf < 4; ++nf) {
    const int n = ocol0 + nf * 16 + c15;
    const float bv = bias[e * DOUT_ + n];
#pragma unroll
    for (int mf = 0; mf < 4; ++mf) {
      const long long mrow = orow0 + mf * 16 + rlo;
#pragma unroll
      for (int j = 0; j < 4; ++j)
        out[(mrow + j) * (long long)DOUT_ + n] = acc[mf][nf][j] + bv;
    }
  }
}

extern "C" void kernel_launch(void* const* d_in, const int* in_sizes, int n_in,
                              void* d_out, int out_size, void* d_ws, size_t ws_size,
                              hipStream_t stream) {
  const float* input  = (const float*)d_in[0];
  const float* weight = (const float*)d_in[1];
  const float* bias   = (const float*)d_in[2];
  const void*  counts = (const void*)d_in[3];
  float* out = (float*)d_out;

  const size_t nA = (size_t)T_ * DIN_;
  const size_t nW = (size_t)E_ * DOUT_ * DIN_;
  const size_t need = (nA + nW) * sizeof(unsigned short);

  if (ws_size >= need) {
    unsigned short* wa = (unsigned short*)d_ws;
    unsigned short* wb = wa + nA;
    const int nA4 = (int)(nA / 4), nW4 = (int)(nW / 4);
    cvt2_kernel<<<dim3((unsigned)((nA4 + nW4) / 256)), dim3(256), 0, stream>>>(
        input, weight, wa, wb, nA4, nW4);
    gemm4_kernel<<<dim3(256), dim3(512), 0, stream>>>(wa, wb, bias, counts, out);
  } else {
    gemm_fb_kernel<<<dim3(E_ * 32 * 32), dim3(256), 0, stream>>>(input, weight, bias, counts, out);
  }
}